// Round 1
// baseline (1504.031 us; speedup 1.0000x reference)
//
#include <hip/hip_runtime.h>

#define NN 100000
#define NE 1600000
#define D 64

// ---------------- degree kernels ----------------

__global__ void k_deg_init(float* __restrict__ deg, int n) {
    int i = blockIdx.x * blockDim.x + threadIdx.x;
    if (i < n) deg[i] = 1.0f;  // self-loop contributes 1 to every node's degree
}

__global__ void k_deg_accum(const int* __restrict__ dst, float* __restrict__ deg, int e) {
    int i = blockIdx.x * blockDim.x + threadIdx.x;
    if (i < e) atomicAdd(&deg[dst[i]], 1.0f);
}

__global__ void k_dinv(float* __restrict__ deg, int n) {
    int i = blockIdx.x * blockDim.x + threadIdx.x;
    if (i < n) deg[i] = rsqrtf(deg[i]);  // deg >= 1 always (self-loops), no zero guard needed
}

// ---------------- projection + self-loop init ----------------
// xw = x @ W ; out = xw * dinv^2 + b   (self-loop message + bias)
// block = 256 threads = 4 rows x 64 cols
__global__ void k_xw_init(const float* __restrict__ x, const float* __restrict__ W,
                          const float* __restrict__ b, const float* __restrict__ dinv,
                          float* __restrict__ xw, float* __restrict__ out, int n) {
    __shared__ float sW[D][D];     // 16 KB
    __shared__ float sx[4][D];     // 1 KB
    int col = threadIdx.x & 63;
    int r   = threadIdx.x >> 6;    // 0..3 (one wave per row)

    for (int i = threadIdx.x; i < D * D; i += 256)
        sW[i >> 6][i & 63] = W[i];

    int row = blockIdx.x * 4 + r;
    if (row < n) sx[r][col] = x[row * D + col];
    __syncthreads();
    if (row >= n) return;

    float acc = 0.f;
#pragma unroll
    for (int k = 0; k < D; ++k)
        acc += sx[r][k] * sW[k][col];   // sx broadcast (wave-uniform), sW 2-way (free)

    xw[row * D + col] = acc;
    float di = dinv[row];
    out[row * D + col] = acc * di * di + b[col];
}

// ---------------- edge scatter ----------------
// 16 threads per edge; each thread handles 4 contiguous columns (float4).
__global__ void k_scatter(const int* __restrict__ src, const int* __restrict__ dst,
                          const float* __restrict__ dinv, const float* __restrict__ xw,
                          float* __restrict__ out, int e) {
    int t = blockIdx.x * blockDim.x + threadIdx.x;
    int edge = t >> 4;
    if (edge >= e) return;
    int lane = t & 15;

    int s = src[edge];
    int d = dst[edge];
    float nrm = dinv[s] * dinv[d];

    const float4* xs = (const float4*)(xw + (size_t)s * D);
    float4 v = xs[lane];

    float* po = out + (size_t)d * D + lane * 4;
    atomicAdd(po + 0, v.x * nrm);
    atomicAdd(po + 1, v.y * nrm);
    atomicAdd(po + 2, v.z * nrm);
    atomicAdd(po + 3, v.w * nrm);
}

extern "C" void kernel_launch(void* const* d_in, const int* in_sizes, int n_in,
                              void* d_out, int out_size, void* d_ws, size_t ws_size,
                              hipStream_t stream) {
    const float* x  = (const float*)d_in[0];
    const int*   ei = (const int*)d_in[1];   // [2, E] row-major: src row then dst row
    const float* W  = (const float*)d_in[2];
    const float* b  = (const float*)d_in[3];
    float* out = (float*)d_out;

    float* xw  = (float*)d_ws;               // N*D floats = 25.6 MB
    float* deg = xw + (size_t)NN * D;        // N floats   = 0.4 MB

    const int* src = ei;
    const int* dst = ei + NE;

    k_deg_init <<<(NN + 255) / 256, 256, 0, stream>>>(deg, NN);
    k_deg_accum<<<(NE + 255) / 256, 256, 0, stream>>>(dst, deg, NE);
    k_dinv     <<<(NN + 255) / 256, 256, 0, stream>>>(deg, NN);
    k_xw_init  <<<(NN + 3) / 4, 256, 0, stream>>>(x, W, b, deg, xw, out, NN);

    long long tot = (long long)NE * 16;
    k_scatter  <<<(int)((tot + 255) / 256), 256, 0, stream>>>(src, dst, deg, xw, out, NE);
}

// Round 2
// 289.937 us; speedup vs baseline: 5.1874x; 5.1874x over previous
//
#include <hip/hip_runtime.h>

#define NN 100000
#define NE 1600000
#define D 64
#define SCAN_B 256
#define NB_SCAN ((NN + SCAN_B - 1) / SCAN_B)   // 391

// ---------------- zero / histogram / dinv ----------------

__global__ void k_zero(int* __restrict__ cnt, int n) {
    int i = blockIdx.x * blockDim.x + threadIdx.x;
    if (i < n) cnt[i] = 0;
}

__global__ void k_hist(const int* __restrict__ dst, int* __restrict__ cnt, int e) {
    int i = blockIdx.x * blockDim.x + threadIdx.x;
    if (i < e) atomicAdd(&cnt[dst[i]], 1);
}

__global__ void k_dinv(const int* __restrict__ cnt, float* __restrict__ dinv, int n) {
    int i = blockIdx.x * blockDim.x + threadIdx.x;
    if (i < n) dinv[i] = rsqrtf((float)cnt[i] + 1.0f);  // +1 = self-loop
}

// ---------------- 3-phase exclusive scan of cnt -> rowstart ----------------

__global__ void k_scan_block(const int* __restrict__ cnt, int* __restrict__ excl,
                             int* __restrict__ bsum, int n) {
    __shared__ int tmp[SCAN_B];
    int tid = threadIdx.x;
    int i = blockIdx.x * SCAN_B + tid;
    int v = (i < n) ? cnt[i] : 0;
    tmp[tid] = v;
    __syncthreads();
    for (int off = 1; off < SCAN_B; off <<= 1) {
        int t = (tid >= off) ? tmp[tid - off] : 0;
        __syncthreads();
        tmp[tid] += t;
        __syncthreads();
    }
    if (i < n) excl[i] = tmp[tid] - v;          // exclusive within block
    if (tid == SCAN_B - 1) bsum[blockIdx.x] = tmp[tid];
}

__global__ void k_scan_bsum(int* __restrict__ bsum, int nb) {
    __shared__ int tmp[512];
    int tid = threadIdx.x;
    int v = (tid < nb) ? bsum[tid] : 0;
    tmp[tid] = v;
    __syncthreads();
    for (int off = 1; off < 512; off <<= 1) {
        int t = (tid >= off) ? tmp[tid - off] : 0;
        __syncthreads();
        tmp[tid] += t;
        __syncthreads();
    }
    if (tid < nb) bsum[tid] = tmp[tid] - v;     // exclusive block offsets
}

__global__ void k_scan_add(int* __restrict__ excl, int* __restrict__ cursor,
                           const int* __restrict__ bsum, int n) {
    int i = blockIdx.x * blockDim.x + threadIdx.x;
    if (i < n) {
        int r = excl[i] + bsum[blockIdx.x * SCAN_B / 256];  // blockDim == 256 == SCAN_B
        excl[i] = r;
        cursor[i] = r;
    }
}

// ---------------- projection: xw = x @ W ----------------
// block = 256 threads = 4 rows x 64 cols
__global__ void k_xw(const float* __restrict__ x, const float* __restrict__ W,
                     float* __restrict__ xw, int n) {
    __shared__ float sW[D][D];
    __shared__ float sx[4][D];
    int col = threadIdx.x & 63;
    int r   = threadIdx.x >> 6;

    for (int i = threadIdx.x; i < D * D; i += 256)
        sW[i >> 6][i & 63] = W[i];

    int row = blockIdx.x * 4 + r;
    if (row < n) sx[r][col] = x[row * D + col];
    __syncthreads();
    if (row >= n) return;

    float acc = 0.f;
#pragma unroll
    for (int k = 0; k < D; ++k)
        acc += sx[r][k] * sW[k][col];
    xw[row * D + col] = acc;
}

// ---------------- CSR build: place {src, norm} records in dst order ----------------

__global__ void k_build(const int* __restrict__ src, const int* __restrict__ dst,
                        const float* __restrict__ dinv, int* __restrict__ cursor,
                        int2* __restrict__ recs, int e) {
    int i = blockIdx.x * blockDim.x + threadIdx.x;
    if (i >= e) return;
    int s = src[i];
    int d = dst[i];
    float nrm = dinv[s] * dinv[d];
    int pos = atomicAdd(&cursor[d], 1);
    recs[pos] = make_int2(s, __float_as_int(nrm));
}

// ---------------- gather-accumulate: one wave per node ----------------

__global__ void k_gather(const int2* __restrict__ recs, const int* __restrict__ rowstart,
                         const int* __restrict__ cnt, const float* __restrict__ dinv,
                         const float* __restrict__ xw, const float* __restrict__ b,
                         float* __restrict__ out, int n) {
    int wid  = (blockIdx.x * blockDim.x + threadIdx.x) >> 6;   // node id
    int lane = threadIdx.x & 63;                                // column
    if (wid >= n) return;

    int base = __builtin_amdgcn_readfirstlane(rowstart[wid]);
    int k    = __builtin_amdgcn_readfirstlane(cnt[wid]);
    float di = dinv[wid];
    float acc = xw[(size_t)wid * D + lane] * di * di + b[lane];  // self-loop + bias

    int i = 0;
    for (; i + 1 < k; i += 2) {
        int2 r0 = recs[base + i];
        int2 r1 = recs[base + i + 1];
        float v0 = xw[(size_t)r0.x * D + lane];
        float v1 = xw[(size_t)r1.x * D + lane];
        acc += v0 * __int_as_float(r0.y);
        acc += v1 * __int_as_float(r1.y);
    }
    if (i < k) {
        int2 r = recs[base + i];
        acc += xw[(size_t)r.x * D + lane] * __int_as_float(r.y);
    }
    out[(size_t)wid * D + lane] = acc;
}

extern "C" void kernel_launch(void* const* d_in, const int* in_sizes, int n_in,
                              void* d_out, int out_size, void* d_ws, size_t ws_size,
                              hipStream_t stream) {
    const float* x  = (const float*)d_in[0];
    const int*   ei = (const int*)d_in[1];   // [2, E]: src row then dst row (int32)
    const float* W  = (const float*)d_in[2];
    const float* b  = (const float*)d_in[3];
    float* out = (float*)d_out;

    // workspace layout (floats/ints, 4B each; recs 8B-aligned)
    float* xw       = (float*)d_ws;                      // N*D           = 6,400,000
    float* dinv     = xw + (size_t)NN * D;               // N
    int*   cnt      = (int*)(dinv + NN);                 // N
    int*   rowstart = cnt + NN;                          // N
    int*   cursor   = rowstart + NN;                     // N
    int*   bsum     = cursor + NN;                       // 512
    int2*  recs     = (int2*)(bsum + 512);               // E int2 = 12.8 MB

    const int* src = ei;
    const int* dst = ei + NE;

    k_zero      <<<(NN + 255) / 256, 256, 0, stream>>>(cnt, NN);
    k_hist      <<<(NE + 255) / 256, 256, 0, stream>>>(dst, cnt, NE);
    k_dinv      <<<(NN + 255) / 256, 256, 0, stream>>>(cnt, dinv, NN);

    k_scan_block<<<NB_SCAN, SCAN_B, 0, stream>>>(cnt, rowstart, bsum, NN);
    k_scan_bsum <<<1, 512, 0, stream>>>(bsum, NB_SCAN);
    k_scan_add  <<<NB_SCAN, SCAN_B, 0, stream>>>(rowstart, cursor, bsum, NN);

    k_xw        <<<(NN + 3) / 4, 256, 0, stream>>>(x, W, xw, NN);
    k_build     <<<(NE + 255) / 256, 256, 0, stream>>>(src, dst, dinv, cursor, recs, NE);

    long long tot = (long long)NN * 64;
    k_gather    <<<(int)((tot + 255) / 256), 256, 0, stream>>>(recs, rowstart, cnt, dinv, xw, b, out, NN);
}